// Round 6
// baseline (979.460 us; speedup 1.0000x reference)
//
#include <hip/hip_runtime.h>
#include <hip/hip_bf16.h>

#define BN    50000
#define NBR   4
#define MM    256
#define DD    32
#define CC    128
#define EE    1000000
#define ROWS  (BN + MM)          // 50256
#define NEDGE (2 * EE)
#define SCAN_BLOCKS 49           // ceil(50000/1024)

// ---- bucketed CSR build geometry (R13) -------------------------------------
#define NBUK  13                 // dst bucket = dst >> 12 (4096 dsts, ~1.3 MB CSR window)
#define NSG   16                 // subgroups per bucket (= blockIdx & 15)
#define NAREA (NBUK * NSG)       // 208 record areas
#define ACAP  15360              // records per area (mean ~10240, +50 sigma)

// ---------------- dtype abstraction (runtime-detected fp32 vs bf16) ----------
template <int ISBF> struct IO;

template <> struct IO<0> {
    static __device__ float ld(const void* p, long i) { return ((const float*)p)[i]; }
    static __device__ float2 ld2(const void* p, long i) {
        const float* f = (const float*)p + i;
        return make_float2(f[0], f[1]);
    }
    static __device__ void st(void* p, long i, float v) { ((float*)p)[i] = v; }
    static __device__ void st2(void* p, long i, float2 v) {
        float* f = (float*)p + i; f[0] = v.x; f[1] = v.y;
    }
};

template <> struct IO<1> {
    static __device__ float b2f(unsigned short u) {
        return __uint_as_float(((unsigned)u) << 16);
    }
    static __device__ unsigned short f2b(float f) {  // round-to-nearest-even
        unsigned x = __float_as_uint(f);
        unsigned r = x + 0x7fffu + ((x >> 16) & 1u);
        return (unsigned short)(r >> 16);
    }
    static __device__ float ld(const void* p, long i) {
        return b2f(((const unsigned short*)p)[i]);
    }
    static __device__ float2 ld2(const void* p, long i) {  // i must be even
        unsigned v = *(const unsigned*)((const unsigned short*)p + i);
        return make_float2(b2f((unsigned short)(v & 0xffffu)),
                           b2f((unsigned short)(v >> 16)));
    }
    static __device__ void st(void* p, long i, float v) {
        ((unsigned short*)p)[i] = f2b(v);
    }
    static __device__ void st2(void* p, long i, float2 v) {
        unsigned o = ((unsigned)f2b(v.x)) | (((unsigned)f2b(v.y)) << 16);
        *(unsigned*)((unsigned short*)p + i) = o;
    }
};

// ---------------- h storage helpers (row-major) ----------------------------
template <int ISBF> struct HIO;
template <> struct HIO<0> {
    static __device__ float2 ld(const float* h, long row, int l) {
        return *(const float2*)(h + row * CC + 2 * l);
    }
    static __device__ void st(float* h, long row, int l, float2 v) {
        *(float2*)(h + row * CC + 2 * l) = v;
    }
};
template <> struct HIO<1> {
    static __device__ float2 ld(const float* h, long row, int l) {
        unsigned u = ((const unsigned*)h)[row * (CC / 2) + l];
        return make_float2(IO<1>::b2f((unsigned short)(u & 0xffffu)),
                           IO<1>::b2f((unsigned short)(u >> 16)));
    }
    static __device__ void st(float* h, long row, int l, float2 v) {
        unsigned o = ((unsigned)IO<1>::f2b(v.x)) | (((unsigned)IO<1>::f2b(v.y)) << 16);
        ((unsigned*)h)[row * (CC / 2) + l] = o;
    }
};

// ---------------- bf16 8-channel helpers (int4 = 8 bf16) --------------------
static __device__ inline void unpack8(int4 v, float* f) {
    unsigned a = (unsigned)v.x, b = (unsigned)v.y, c = (unsigned)v.z, d = (unsigned)v.w;
    f[0] = IO<1>::b2f((unsigned short)(a & 0xffffu)); f[1] = IO<1>::b2f((unsigned short)(a >> 16));
    f[2] = IO<1>::b2f((unsigned short)(b & 0xffffu)); f[3] = IO<1>::b2f((unsigned short)(b >> 16));
    f[4] = IO<1>::b2f((unsigned short)(c & 0xffffu)); f[5] = IO<1>::b2f((unsigned short)(c >> 16));
    f[6] = IO<1>::b2f((unsigned short)(d & 0xffffu)); f[7] = IO<1>::b2f((unsigned short)(d >> 16));
}
static __device__ inline void fma8(float* acc, float w, int4 v) {
    float f[8]; unpack8(v, f);
#pragma unroll
    for (int k = 0; k < 8; k++) acc[k] += w * f[k];
}
static __device__ inline float dot8(const float* hi, int4 v) {
    float f[8]; unpack8(v, f);
    float s = 0.f;
#pragma unroll
    for (int k = 0; k < 8; k++) s += hi[k] * f[k];
    return s;
}

// ---------------- dtype detect: warm_up_rate == 1.0 -------------------------
__global__ void kDetect(const void* warm, int* flag) {
    flag[0] = (((const unsigned short*)warm)[0] == 0x3F80u) ? 1 : 0;
}

// ---------------- kernel A ---------------------------------------------------
// h batch rows (r < BN) -> d_out (row-major); codeword rows -> ws hcw
template <int ISBF>
__device__ void kA_body(const void* X_B, const void* codebook, const void* W_conv,
                        const void* warm, float* __restrict__ hout,
                        float* __restrict__ hcw, float* sW, float* sX) {
    int tid = threadIdx.x;
    int w = tid >> 6, l = tid & 63;
    for (int k = tid; k < NBR * DD * DD; k += 256)
        sW[k] = IO<ISBF>::ld(W_conv, k);
    int r = blockIdx.x * 4 + w;
    int c0 = 2 * l, n = c0 >> 5, e = c0 & 31;
    float2 x2;
    if (r < BN) {
        x2 = IO<ISBF>::ld2(X_B, (long)r * CC + c0);
    } else {
        int m = r - BN;
        float wr = IO<ISBF>::ld(warm, 0);
        x2 = IO<ISBF>::ld2(codebook, (long)n * MM * DD + m * DD + e);
        x2.x *= wr; x2.y *= wr;
    }
    sX[w * CC + c0] = x2.x;
    sX[w * CC + c0 + 1] = x2.y;
    __syncthreads();
    float2 acc = make_float2(0.f, 0.f);
#pragma unroll
    for (int d = 0; d < DD; d++) {
        float xv = sX[w * CC + n * DD + d];
        float2 wv = *(const float2*)&sW[n * DD * DD + d * DD + e];
        acc.x += xv * wv.x;
        acc.y += xv * wv.y;
    }
    if (r < BN) HIO<ISBF>::st(hout, r, l, acc);
    else        HIO<ISBF>::st(hcw, r - BN, l, acc);
}
__global__ __launch_bounds__(256) void kA(const int* flag, const void* X_B,
                                          const void* codebook, const void* W_conv,
                                          const void* warm, float* hout, float* hcw) {
    __shared__ float sW[NBR * DD * DD];
    __shared__ float sX[4 * CC];
    if (*flag) kA_body<1>(X_B, codebook, W_conv, warm, hout, hcw, sW, sX);
    else       kA_body<0>(X_B, codebook, W_conv, warm, hout, hcw, sW, sX);
}

// ---- P1: stream edges once -> dst histogram + bucketed 8 B records ---------
// R4 post-mortem: kFill's 2M random 8 B scatters over 16 MB write-amplify ~8x
// (R3 outlier: 127 MB WRITE for 16 MB of entries) — same beyond-L2 transaction
// wall as the gather. P1 appends records into per-(bucket,subgroup) areas via
// LDS staging + coalesced flushes; P2 scatters them inside a per-bucket ~1.3 MB
// CSR window that stays L2-resident. rec = {w:f32 | dstLow12:12 | src:17}.
template <int ISBF>
__device__ void kP1_body(const int* esrc_bb, const int* edst_bb, const void* ew_bb,
                         const int* esrc_bm, const int* edst_bm, const void* ew_bm,
                         const int* c_idx, int* __restrict__ counts,
                         int* __restrict__ areaCur, long* __restrict__ recs,
                         long* stage, int* lcnt) {
    int tid = threadIdx.x;
    int wv = tid >> 6, lane = tid & 63;
    int sg = blockIdx.x & (NSG - 1);
    for (long i0 = (long)blockIdx.x * 256; i0 < NEDGE; i0 += (long)gridDim.x * 256) {
        if (tid < NBUK) lcnt[tid] = 0;
        __syncthreads();
        long i = i0 + tid;
        int b = -1, dst = 0;
        if (i < NEDGE) {
            int src; float w;
            if (i < EE) {
                src = esrc_bb[i]; dst = edst_bb[i]; w = IO<ISBF>::ld(ew_bb, i);
            } else {
                long j = i - EE;
                src = BN + c_idx[esrc_bm[j]]; dst = edst_bm[j]; w = IO<ISBF>::ld(ew_bm, j);
            }
            b = dst >> 12;
            unsigned pk = ((unsigned)(dst & 4095) << 17) | (unsigned)src;
            long rec = ((long)__float_as_int(w) << 32) | (unsigned long long)pk;
            int slot = atomicAdd(&lcnt[b], 1);
            stage[b * 256 + slot] = rec;
            atomicAdd(&counts[dst], 1);
        }
        __syncthreads();
        // flush: wave wv handles buckets wv, wv+4, ...
        for (int bk = wv; bk < NBUK; bk += 4) {
            int cnt = lcnt[bk];
            if (cnt == 0) continue;
            int gb = 0;
            if (lane == 0) gb = atomicAdd(&areaCur[(bk * NSG + sg) * 16], cnt);
            gb = __shfl(gb, 0);
            long* dstp = recs + (long)(bk * NSG + sg) * ACAP + gb;
            for (int k = lane; k < cnt; k += 64) dstp[k] = stage[bk * 256 + k];
        }
        __syncthreads();
    }
}
__global__ __launch_bounds__(256) void kP1(const int* flag, const int* esrc_bb,
                                           const int* edst_bb, const void* ew_bb,
                                           const int* esrc_bm, const int* edst_bm,
                                           const void* ew_bm, const int* c_idx,
                                           int* counts, int* areaCur, long* recs) {
    __shared__ long stage[NBUK * 256];   // 26.6 KB
    __shared__ int lcnt[NBUK];
    if (*flag) kP1_body<1>(esrc_bb, edst_bb, ew_bb, esrc_bm, edst_bm, ew_bm,
                           c_idx, counts, areaCur, recs, stage, lcnt);
    else       kP1_body<0>(esrc_bb, edst_bb, ew_bb, esrc_bm, edst_bm, ew_bm,
                           c_idx, counts, areaCur, recs, stage, lcnt);
}

// ---------------- 3-kernel exclusive scan over counts[BN] -------------------
__global__ __launch_bounds__(1024) void kScan1(const int* __restrict__ counts,
                                               int* __restrict__ offsets,
                                               int* __restrict__ tileSum) {
    __shared__ int s[1024];
    int tid = threadIdx.x;
    int i = blockIdx.x * 1024 + tid;
    int v = (i < BN) ? counts[i] : 0;
    s[tid] = v;
    __syncthreads();
    for (int off = 1; off < 1024; off <<= 1) {
        int x = (tid >= off) ? s[tid - off] : 0;
        __syncthreads();
        s[tid] += x;
        __syncthreads();
    }
    if (i < BN) offsets[i] = s[tid] - v;  // tile-local exclusive
    if (tid == 1023) tileSum[blockIdx.x] = s[tid];
}
__global__ void kScan2(int* tileSum) {
    int run = 0;
    for (int t = 0; t < SCAN_BLOCKS; t++) {
        int v = tileSum[t];
        tileSum[t] = run;
        run += v;
    }
}
__global__ __launch_bounds__(1024) void kScan3(int* __restrict__ offsets,
                                               const int* __restrict__ tileSum,
                                               int* __restrict__ cursor) {
    int i = blockIdx.x * 1024 + threadIdx.x;
    if (i < BN) {
        int o = offsets[i] + tileSum[blockIdx.x];
        offsets[i] = o;
        cursor[i] = o;
    }
}

// ---- P2: distribute bucket records into CSR entries (L2-contained scatter) --
// One block per bucket; all scattered stores land inside this bucket's
// contiguous CSR window (~1.3 MB) -> resident in the owning XCD's L2.
__global__ __launch_bounds__(1024) void kP2(const int* __restrict__ areaCur,
                                            const long* __restrict__ recs,
                                            int* __restrict__ cursor,
                                            long* __restrict__ entries) {
    int b = blockIdx.x;
    for (int sg = 0; sg < NSG; sg++) {
        int n = areaCur[(b * NSG + sg) * 16];
        const long* rp = recs + (long)(b * NSG + sg) * ACAP;
#pragma unroll 4
        for (int k = threadIdx.x; k < n; k += 1024) {
            long rec = rp[k];
            unsigned pk = (unsigned)(rec & 0xffffffffL);
            int dst = (b << 12) | (int)(pk >> 17);
            int src = (int)(pk & 0x1ffffu);
            int pos = atomicAdd(&cursor[dst], 1);
            entries[pos] = (rec & 0xffffffff00000000L) | (unsigned)src;  // {w|src}
        }
    }
}

// ---- gather (R1 winner, unchanged): persistent waves, 8-deep chunks --------
__device__ void kG_body_bf(const unsigned short* __restrict__ hbatch,   // d_out
                           const unsigned short* __restrict__ hcw,      // ws, 64 KB (L2-hot)
                           const long* __restrict__ entries,
                           const int* __restrict__ offsets, const int* __restrict__ counts,
                           const void* b_conv, const void* vq_grad, void* t,
                           float* __restrict__ infoP) {
    int tid = threadIdx.x;
    int l = tid & 63;
    int g = l >> 4;                 // edge-group 0..3
    int q = l & 15;                 // lane-in-group
    int c0 = q * 8;                 // 8 channels per lane
    int n = c0 >> 5, e0 = c0 & 31;
    const unsigned short* gb = (const unsigned short*)vq_grad + (long)n * MM * DD + e0;

    int wid = (int)((blockIdx.x * blockDim.x + tid) >> 6);
    int nw  = (int)((gridDim.x * blockDim.x) >> 6);

    for (int i = wid; i < BN; i += nw) {
        int start = __builtin_amdgcn_readfirstlane(offsets[i]);
        int deg   = __builtin_amdgcn_readfirstlane(counts[i]);
        const long* ep = entries + start;

        float hi[8];                // own row (batch), for info term
        unpack8(*(const int4*)(hbatch + (long)i * CC + c0), hi);
        float acc[8] = {0.f, 0.f, 0.f, 0.f, 0.f, 0.f, 0.f, 0.f};
        float info = 0.f;

        for (int j = 0; j < deg; j += 32) {
            int src[8]; float wj[8];
#pragma unroll
            for (int u = 0; u < 8; u++) {
                int idx = j + 4 * u + g;
                long e8 = __builtin_nontemporal_load(ep + (idx < deg ? idx : deg - 1));
                src[u] = (int)(unsigned)(e8 & 0xffffffffL);
                wj[u]  = (idx < deg) ? __int_as_float((int)(e8 >> 32)) : 0.f;
            }
#pragma unroll
            for (int u = 0; u < 8; u++) {
                int4 hv;
                if (src[u] < BN) {
                    hv = *(const int4*)(hbatch + (long)src[u] * CC + c0);
                } else {
                    hv = *(const int4*)(hcw + (long)(src[u] - BN) * CC + c0);
                    if (wj[u] != 0.f) {
                        int4 gv = *(const int4*)(gb + (long)(src[u] - BN) * DD);
                        info += wj[u] * dot8(hi, gv);
                    }
                }
                fma8(acc, wj[u], hv);
            }
        }
        // merge the 4 group-accumulators
#pragma unroll
        for (int k = 0; k < 8; k++) {
            acc[k] += __shfl_xor(acc[k], 16);
            acc[k] += __shfl_xor(acc[k], 32);
        }
        for (int off = 32; off; off >>= 1) info += __shfl_xor(info, off);
        if (l == 0) infoP[i] = info;    // plain store — NO atomic
        if (g == 0) {                   // lanes 0-15 write the 256 B t row
            float bc[8];
            unpack8(*(const int4*)((const unsigned short*)b_conv + n * DD + e0), bc);
            unsigned o[4];
#pragma unroll
            for (int d = 0; d < 4; d++)
                o[d] = ((unsigned)IO<1>::f2b(acc[2 * d] + bc[2 * d])) |
                       (((unsigned)IO<1>::f2b(acc[2 * d + 1] + bc[2 * d + 1])) << 16);
            *(int4*)((unsigned short*)t + (long)i * CC + c0) = make_int4(o[0], o[1], o[2], o[3]);
        }
    }
}

// fp32 fallback (correctness-only path)
__device__ void kG_body_f32(const float* __restrict__ hbatch, const float* __restrict__ hcw,
                            const long* __restrict__ entries,
                            const int* __restrict__ offsets, const int* __restrict__ counts,
                            const void* b_conv, const void* vq_grad, void* t,
                            float* __restrict__ infoP) {
    int tid = threadIdx.x;
    int l = tid & 63;
    int c0 = 2 * l, n = c0 >> 5, e = c0 & 31;
    int wid = (int)((blockIdx.x * blockDim.x + tid) >> 6);
    int nw  = (int)((gridDim.x * blockDim.x) >> 6);
    for (int i = wid; i < BN; i += nw) {
        int start = __builtin_amdgcn_readfirstlane(offsets[i]);
        int deg   = __builtin_amdgcn_readfirstlane(counts[i]);
        const long* ep = entries + start;
        float2 hi = HIO<0>::ld(hbatch, i, l);
        long gbase = (long)n * MM * DD + e;
        float2 acc = make_float2(0.f, 0.f);
        float info = 0.f;
        for (int j = 0; j < deg; j++) {
            long e8 = ep[j];
            int sv = (int)(unsigned)(e8 & 0xffffffffL);
            float wj = __int_as_float((int)(e8 >> 32));
            const float* src = (sv < BN) ? (hbatch + (long)sv * CC)
                                         : (hcw + (long)(sv - BN) * CC);
            float2 hv = *(const float2*)(src + c0);
            acc.x += wj * hv.x;
            acc.y += wj * hv.y;
            if (sv >= BN) {
                float2 gv = IO<0>::ld2(vq_grad, gbase + (long)(sv - BN) * DD);
                info += wj * (hi.x * gv.x + hi.y * gv.y);
            }
        }
        float2 b2 = IO<0>::ld2(b_conv, n * DD + e);
        IO<0>::st2(t, (long)i * CC + c0, make_float2(acc.x + b2.x, acc.y + b2.y));
        for (int off = 32; off; off >>= 1) info += __shfl_xor(info, off);
        if (l == 0) infoP[i] = info;
    }
}
__global__ __launch_bounds__(256, 8) void kGather(const int* flag, const float* hout,
                                                  const float* hcw, const long* entries,
                                                  const int* offsets, const int* counts,
                                                  const void* b_conv, const void* vq_grad,
                                                  void* t, float* infoP) {
    if (*flag) kG_body_bf((const unsigned short*)hout, (const unsigned short*)hcw,
                          entries, offsets, counts, b_conv, vq_grad, t, infoP);
    else       kG_body_f32(hout, hcw, entries, offsets, counts, b_conv, vq_grad, t, infoP);
}

// ---- reduce infoP[BN] -> ibAcc (49 blocks, one atomic each) ----------------
__global__ __launch_bounds__(1024) void kRed(const float* __restrict__ infoP, float* ibAcc) {
    __shared__ float s[1024];
    int tid = threadIdx.x;
    int i = blockIdx.x * 1024 + tid;
    s[tid] = (i < BN) ? infoP[i] : 0.f;
    __syncthreads();
    for (int st = 512; st; st >>= 1) {
        if (tid < st) s[tid] += s[tid + st];
        __syncthreads();
    }
    if (tid == 0) atomicAdd(ibAcc, s[0]);
}

// ---- FC: Y = t @ W_fc + b_fc + X_B ; t from ws, Y -> d_out -----------------
template <int ISBF>
__device__ void kFC_body(const void* t, const void* W_fc, const void* b_fc,
                         const void* X_B, void* Y, float* sT, float* sW) {
    int tid = threadIdx.x;
    int w = tid >> 6, l = tid & 63;
    int c0 = 2 * l;
    int r0 = blockIdx.x * 32;
    for (int k = tid; k < 32 * CC / 2; k += 512) {
        int row = k >> 6, c = (k & 63) * 2;
        float2 v = make_float2(0.f, 0.f);
        if (r0 + row < BN) v = IO<ISBF>::ld2(t, (long)(r0 + row) * CC + c);
        sT[row * CC + c] = v.x;
        sT[row * CC + c + 1] = v.y;
    }
    float2 y[4];
#pragma unroll
    for (int rr = 0; rr < 4; rr++) y[rr] = make_float2(0.f, 0.f);
    for (int ch = 0; ch < 4; ch++) {
        __syncthreads();   // ch==0: publishes sT; ch>0: protects prior sW reads
        for (int k = tid; k < 32 * CC / 2; k += 512) {
            int cc = k >> 6, c = (k & 63) * 2;
            float2 v = IO<ISBF>::ld2(W_fc, (long)(ch * 32 + cc) * CC + c);
            sW[cc * CC + c] = v.x;
            sW[cc * CC + c + 1] = v.y;
        }
        __syncthreads();
#pragma unroll 8
        for (int cc = 0; cc < 32; cc++) {
            float2 wv = *(const float2*)&sW[cc * CC + c0];
#pragma unroll
            for (int rr = 0; rr < 4; rr++) {
                float tv = sT[(w * 4 + rr) * CC + ch * 32 + cc];  // wave-broadcast
                y[rr].x += tv * wv.x;
                y[rr].y += tv * wv.y;
            }
        }
    }
    float2 bf = IO<ISBF>::ld2(b_fc, c0);
#pragma unroll
    for (int rr = 0; rr < 4; rr++) {
        int r = r0 + w * 4 + rr;
        if (r < BN) {
            float2 xb = IO<ISBF>::ld2(X_B, (long)r * CC + c0);
            IO<ISBF>::st2(Y, (long)r * CC + c0,
                          make_float2(y[rr].x + bf.x + xb.x, y[rr].y + bf.y + xb.y));
        }
    }
}
__global__ __launch_bounds__(512) void kFC(const int* flag, const void* t, const void* W_fc,
                                           const void* b_fc, const void* X_B, void* Y) {
    __shared__ float sT[32 * CC];
    __shared__ float sW[32 * CC];
    if (*flag) kFC_body<1>(t, W_fc, b_fc, X_B, Y, sT, sW);
    else       kFC_body<0>(t, W_fc, b_fc, X_B, Y, sT, sW);
}

// ---------------- finalize: + b_conv·vq_grad term, scale by wr --------------
template <int ISBF>
__device__ void kF_body(const void* b_conv, const void* vq_grad, const void* warm,
                        const float* ibAcc, void* out, float* sred) {
    int tid = threadIdx.x;
    float a = 0.f;
    for (int idx = tid; idx < NBR * MM * DD; idx += 256) {
        int nn = idx >> 13, dd = idx & 31;
        a += IO<ISBF>::ld(b_conv, nn * DD + dd) * IO<ISBF>::ld(vq_grad, idx);
    }
    sred[tid] = a;
    __syncthreads();
    for (int s = 128; s; s >>= 1) {
        if (tid < s) sred[tid] += sred[tid + s];
        __syncthreads();
    }
    if (tid == 0) {
        float wr = IO<ISBF>::ld(warm, 0);
        IO<ISBF>::st(out, (long)BN * CC, wr * (ibAcc[0] + sred[0]));
    }
}
__global__ __launch_bounds__(256) void kFinal(const int* flag, const void* b_conv,
                                              const void* vq_grad, const void* warm,
                                              const float* ibAcc, void* out) {
    __shared__ float sred[256];
    if (*flag) kF_body<1>(b_conv, vq_grad, warm, ibAcc, out, sred);
    else       kF_body<0>(b_conv, vq_grad, warm, ibAcc, out, sred);
}

// ---------------- launch --------------------------------------------------
extern "C" void kernel_launch(void* const* d_in, const int* in_sizes, int n_in,
                              void* d_out, int out_size, void* d_ws, size_t ws_size,
                              hipStream_t stream) {
    (void)in_sizes; (void)n_in; (void)out_size;
    const void* X_B      = d_in[0];
    const int*  esrc_bb  = (const int*)d_in[1];
    const int*  edst_bb  = (const int*)d_in[2];
    const void* ew_bb    = d_in[3];
    const int*  esrc_bm  = (const int*)d_in[4];
    const int*  edst_bm  = (const int*)d_in[5];
    const void* ew_bm    = d_in[6];
    const int*  c_idx    = (const int*)d_in[7];
    const void* warm     = d_in[8];
    const void* codebook = d_in[9];
    const void* vq_grad  = d_in[10];
    const void* W_conv   = d_in[11];
    const void* b_conv   = d_in[12];
    const void* W_fc     = d_in[13];
    const void* b_fc     = d_in[14];

    char* ws = (char*)d_ws;
    float* hcw     = (float*)ws;  ws += (size_t)MM * CC * 4;       // 128 KiB (fp32 worst)
    float* tbuf    = (float*)ws;  ws += (size_t)BN * CC * 4;       // 25.6 MB (recs alias)
    long*  entries = (long*)ws;   ws += (size_t)NEDGE * 8;         // 16 MB
    int*   counts  = (int*)ws;    ws += (size_t)BN * 4;
    int*   offsets = (int*)ws;    ws += (size_t)BN * 4;
    int*   cursor  = (int*)ws;    ws += (size_t)BN * 4;
    float* infoP   = (float*)ws;  ws += (size_t)BN * 4;            // 200 KB partials
    int*   tileSum = (int*)ws;    ws += 64 * 4;
    int*   areaCur = (int*)ws;    ws += (size_t)NAREA * 16 * 4;    // 13.3 KB (64B-padded)
    float* ibAcc   = (float*)ws;  ws += 16;
    int*   flag    = (int*)ws;    ws += 16;
    if ((size_t)(ws - (char*)d_ws) > ws_size) return;  // ws too small: bail

    long* recs = (long*)tbuf;      // records alias tbuf (dead until kGather)
    float* hout = (float*)d_out;   // batch h-rows live in d_out until kFC overwrites

    hipMemsetAsync(counts, 0, (size_t)BN * 4, stream);
    hipMemsetAsync(areaCur, 0, (size_t)NAREA * 16 * 4, stream);
    hipMemsetAsync(ibAcc, 0, 4, stream);
    kDetect<<<1, 1, 0, stream>>>(warm, flag);
    kA<<<ROWS / 4, 256, 0, stream>>>(flag, X_B, codebook, W_conv, warm, hout, hcw);
    kP1<<<1024, 256, 0, stream>>>(flag, esrc_bb, edst_bb, ew_bb, esrc_bm, edst_bm,
                                  ew_bm, c_idx, counts, areaCur, recs);
    kScan1<<<SCAN_BLOCKS, 1024, 0, stream>>>(counts, offsets, tileSum);
    kScan2<<<1, 1, 0, stream>>>(tileSum);
    kScan3<<<SCAN_BLOCKS, 1024, 0, stream>>>(offsets, tileSum, cursor);
    kP2<<<NBUK, 1024, 0, stream>>>(areaCur, recs, cursor, entries);
    kGather<<<2048, 256, 0, stream>>>(flag, hout, hcw, entries, offsets, counts,
                                      b_conv, vq_grad, tbuf, infoP);
    kRed<<<SCAN_BLOCKS, 1024, 0, stream>>>(infoP, ibAcc);
    kFC<<<(BN + 31) / 32, 512, 0, stream>>>(flag, tbuf, W_fc, b_fc, X_B, d_out);
    kFinal<<<1, 256, 0, stream>>>(flag, b_conv, vq_grad, warm, ibAcc, d_out);
}

// Round 7
// 623.915 us; speedup vs baseline: 1.5699x; 1.5699x over previous
//
#include <hip/hip_runtime.h>
#include <hip/hip_bf16.h>

#define BN    50000
#define NBR   4
#define MM    256
#define DD    32
#define CC    128
#define EE    1000000
#define ROWS  (BN + MM)          // 50256
#define NEDGE (2 * EE)
#define SCAN_BLOCKS 49           // ceil(50000/1024)

// ---- bucketed CSR build geometry -------------------------------------------
#define NBUK  13                 // dst bucket = dst >> 12 (4096 dsts, ~1.3 MB CSR window)
#define NSG   16                 // subgroups per bucket
#define NAREA (NBUK * NSG)       // 208 record areas
#define ACAP  15360              // records per area (mean ~9.6K, huge margin)

// ---------------- dtype abstraction (runtime-detected fp32 vs bf16) ----------
template <int ISBF> struct IO;

template <> struct IO<0> {
    static __device__ float ld(const void* p, long i) { return ((const float*)p)[i]; }
    static __device__ float2 ld2(const void* p, long i) {
        const float* f = (const float*)p + i;
        return make_float2(f[0], f[1]);
    }
    static __device__ void st(void* p, long i, float v) { ((float*)p)[i] = v; }
    static __device__ void st2(void* p, long i, float2 v) {
        float* f = (float*)p + i; f[0] = v.x; f[1] = v.y;
    }
};

template <> struct IO<1> {
    static __device__ float b2f(unsigned short u) {
        return __uint_as_float(((unsigned)u) << 16);
    }
    static __device__ unsigned short f2b(float f) {  // round-to-nearest-even
        unsigned x = __float_as_uint(f);
        unsigned r = x + 0x7fffu + ((x >> 16) & 1u);
        return (unsigned short)(r >> 16);
    }
    static __device__ float ld(const void* p, long i) {
        return b2f(((const unsigned short*)p)[i]);
    }
    static __device__ float2 ld2(const void* p, long i) {  // i must be even
        unsigned v = *(const unsigned*)((const unsigned short*)p + i);
        return make_float2(b2f((unsigned short)(v & 0xffffu)),
                           b2f((unsigned short)(v >> 16)));
    }
    static __device__ void st(void* p, long i, float v) {
        ((unsigned short*)p)[i] = f2b(v);
    }
    static __device__ void st2(void* p, long i, float2 v) {
        unsigned o = ((unsigned)f2b(v.x)) | (((unsigned)f2b(v.y)) << 16);
        *(unsigned*)((unsigned short*)p + i) = o;
    }
};

// ---------------- h storage helpers (row-major) ----------------------------
template <int ISBF> struct HIO;
template <> struct HIO<0> {
    static __device__ float2 ld(const float* h, long row, int l) {
        return *(const float2*)(h + row * CC + 2 * l);
    }
    static __device__ void st(float* h, long row, int l, float2 v) {
        *(float2*)(h + row * CC + 2 * l) = v;
    }
};
template <> struct HIO<1> {
    static __device__ float2 ld(const float* h, long row, int l) {
        unsigned u = ((const unsigned*)h)[row * (CC / 2) + l];
        return make_float2(IO<1>::b2f((unsigned short)(u & 0xffffu)),
                           IO<1>::b2f((unsigned short)(u >> 16)));
    }
    static __device__ void st(float* h, long row, int l, float2 v) {
        unsigned o = ((unsigned)IO<1>::f2b(v.x)) | (((unsigned)IO<1>::f2b(v.y)) << 16);
        ((unsigned*)h)[row * (CC / 2) + l] = o;
    }
};

// ---------------- bf16 8-channel helpers (int4 = 8 bf16) --------------------
static __device__ inline void unpack8(int4 v, float* f) {
    unsigned a = (unsigned)v.x, b = (unsigned)v.y, c = (unsigned)v.z, d = (unsigned)v.w;
    f[0] = IO<1>::b2f((unsigned short)(a & 0xffffu)); f[1] = IO<1>::b2f((unsigned short)(a >> 16));
    f[2] = IO<1>::b2f((unsigned short)(b & 0xffffu)); f[3] = IO<1>::b2f((unsigned short)(b >> 16));
    f[4] = IO<1>::b2f((unsigned short)(c & 0xffffu)); f[5] = IO<1>::b2f((unsigned short)(c >> 16));
    f[6] = IO<1>::b2f((unsigned short)(d & 0xffffu)); f[7] = IO<1>::b2f((unsigned short)(d >> 16));
}
static __device__ inline void fma8(float* acc, float w, int4 v) {
    float f[8]; unpack8(v, f);
#pragma unroll
    for (int k = 0; k < 8; k++) acc[k] += w * f[k];
}
static __device__ inline float dot8(const float* hi, int4 v) {
    float f[8]; unpack8(v, f);
    float s = 0.f;
#pragma unroll
    for (int k = 0; k < 8; k++) s += hi[k] * f[k];
    return s;
}

// ---------------- MFMA types -------------------------------------------------
typedef short bf16x8 __attribute__((ext_vector_type(8)));
typedef float f32x4  __attribute__((ext_vector_type(4)));

// ---------------- dtype detect: warm_up_rate == 1.0 -------------------------
__global__ void kDetect(const void* warm, int* flag) {
    flag[0] = (((const unsigned short*)warm)[0] == 0x3F80u) ? 1 : 0;
}

// ---------------- kernel A ---------------------------------------------------
// h batch rows (r < BN) -> d_out (row-major); codeword rows -> ws hcw
template <int ISBF>
__device__ void kA_body(const void* X_B, const void* codebook, const void* W_conv,
                        const void* warm, float* __restrict__ hout,
                        float* __restrict__ hcw, float* sW, float* sX) {
    int tid = threadIdx.x;
    int w = tid >> 6, l = tid & 63;
    for (int k = tid; k < NBR * DD * DD; k += 256)
        sW[k] = IO<ISBF>::ld(W_conv, k);
    int r = blockIdx.x * 4 + w;
    int c0 = 2 * l, n = c0 >> 5, e = c0 & 31;
    float2 x2;
    if (r < BN) {
        x2 = IO<ISBF>::ld2(X_B, (long)r * CC + c0);
    } else {
        int m = r - BN;
        float wr = IO<ISBF>::ld(warm, 0);
        x2 = IO<ISBF>::ld2(codebook, (long)n * MM * DD + m * DD + e);
        x2.x *= wr; x2.y *= wr;
    }
    sX[w * CC + c0] = x2.x;
    sX[w * CC + c0 + 1] = x2.y;
    __syncthreads();
    float2 acc = make_float2(0.f, 0.f);
#pragma unroll
    for (int d = 0; d < DD; d++) {
        float xv = sX[w * CC + n * DD + d];
        float2 wv = *(const float2*)&sW[n * DD * DD + d * DD + e];
        acc.x += xv * wv.x;
        acc.y += xv * wv.y;
    }
    if (r < BN) HIO<ISBF>::st(hout, r, l, acc);
    else        HIO<ISBF>::st(hcw, r - BN, l, acc);
}
__global__ __launch_bounds__(256) void kA(const int* flag, const void* X_B,
                                          const void* codebook, const void* W_conv,
                                          const void* warm, float* hout, float* hcw) {
    __shared__ float sW[NBR * DD * DD];
    __shared__ float sX[4 * CC];
    if (*flag) kA_body<1>(X_B, codebook, W_conv, warm, hout, hcw, sW, sX);
    else       kA_body<0>(X_B, codebook, W_conv, warm, hout, hcw, sW, sX);
}

// ---- P1: stream edges once -> dst histogram + bucketed 8 B records ---------
// LDS staging + coalesced area appends (verified correct in R13).
template <int ISBF>
__device__ void kP1_body(const int* esrc_bb, const int* edst_bb, const void* ew_bb,
                         const int* esrc_bm, const int* edst_bm, const void* ew_bm,
                         const int* c_idx, int* __restrict__ counts,
                         int* __restrict__ areaCur, long* __restrict__ recs,
                         long* stage, int* lcnt) {
    int tid = threadIdx.x;
    int wv = tid >> 6, lane = tid & 63;
    int sg = blockIdx.x & (NSG - 1);
    for (long i0 = (long)blockIdx.x * 256; i0 < NEDGE; i0 += (long)gridDim.x * 256) {
        if (tid < NBUK) lcnt[tid] = 0;
        __syncthreads();
        long i = i0 + tid;
        if (i < NEDGE) {
            int src, dst; float w;
            if (i < EE) {
                src = esrc_bb[i]; dst = edst_bb[i]; w = IO<ISBF>::ld(ew_bb, i);
            } else {
                long j = i - EE;
                src = BN + c_idx[esrc_bm[j]]; dst = edst_bm[j]; w = IO<ISBF>::ld(ew_bm, j);
            }
            int b = dst >> 12;
            unsigned pk = ((unsigned)(dst & 4095) << 17) | (unsigned)src;
            long rec = ((long)__float_as_int(w) << 32) | (unsigned long long)pk;
            int slot = atomicAdd(&lcnt[b], 1);
            stage[b * 256 + slot] = rec;
            atomicAdd(&counts[dst], 1);
        }
        __syncthreads();
        // flush: wave wv handles buckets wv, wv+4, ...
        for (int bk = wv; bk < NBUK; bk += 4) {
            int cnt = lcnt[bk];
            if (cnt == 0) continue;
            int gb = 0;
            if (lane == 0) gb = atomicAdd(&areaCur[(bk * NSG + sg) * 16], cnt);
            gb = __shfl(gb, 0);
            long* dstp = recs + (long)(bk * NSG + sg) * ACAP + gb;
            for (int k = lane; k < cnt; k += 64) dstp[k] = stage[bk * 256 + k];
        }
        __syncthreads();
    }
}
__global__ __launch_bounds__(256) void kP1(const int* flag, const int* esrc_bb,
                                           const int* edst_bb, const void* ew_bb,
                                           const int* esrc_bm, const int* edst_bm,
                                           const void* ew_bm, const int* c_idx,
                                           int* counts, int* areaCur, long* recs) {
    __shared__ long stage[NBUK * 256];   // 26.6 KB
    __shared__ int lcnt[NBUK];
    if (*flag) kP1_body<1>(esrc_bb, edst_bb, ew_bb, esrc_bm, edst_bm, ew_bm,
                           c_idx, counts, areaCur, recs, stage, lcnt);
    else       kP1_body<0>(esrc_bb, edst_bb, ew_bb, esrc_bm, edst_bm, ew_bm,
                           c_idx, counts, areaCur, recs, stage, lcnt);
}

// ---------------- 3-kernel exclusive scan over counts[BN] -------------------
__global__ __launch_bounds__(1024) void kScan1(const int* __restrict__ counts,
                                               int* __restrict__ offsets,
                                               int* __restrict__ tileSum) {
    __shared__ int s[1024];
    int tid = threadIdx.x;
    int i = blockIdx.x * 1024 + tid;
    int v = (i < BN) ? counts[i] : 0;
    s[tid] = v;
    __syncthreads();
    for (int off = 1; off < 1024; off <<= 1) {
        int x = (tid >= off) ? s[tid - off] : 0;
        __syncthreads();
        s[tid] += x;
        __syncthreads();
    }
    if (i < BN) offsets[i] = s[tid] - v;  // tile-local exclusive
    if (tid == 1023) tileSum[blockIdx.x] = s[tid];
}
__global__ void kScan2(int* tileSum) {
    int run = 0;
    for (int t = 0; t < SCAN_BLOCKS; t++) {
        int v = tileSum[t];
        tileSum[t] = run;
        run += v;
    }
}
__global__ __launch_bounds__(1024) void kScan3(int* __restrict__ offsets,
                                               const int* __restrict__ tileSum,
                                               int* __restrict__ cursor) {
    int i = blockIdx.x * 1024 + threadIdx.x;
    if (i < BN) {
        int o = offsets[i] + tileSum[blockIdx.x];
        offsets[i] = o;
        cursor[i] = o;
    }
}

// ---- P2: distribute bucket records into CSR entries ------------------------
// R5 post-mortem: 13 blocks = 1.9% occupancy = 457 us. Fix: one block per
// (bucket,subgroup) AREA (208 blocks) — areas are private, no new races;
// scatters still confined to the bucket's ~1.3 MB CSR window.
__global__ __launch_bounds__(256) void kP2(const int* __restrict__ areaCur,
                                           const long* __restrict__ recs,
                                           int* __restrict__ cursor,
                                           long* __restrict__ entries) {
    int a = blockIdx.x;                 // a = b*NSG + sg
    int b = a / NSG;
    int n = areaCur[a * 16];
    const long* rp = recs + (long)a * ACAP;
    for (int k = threadIdx.x; k < n; k += 256) {
        long rec = rp[k];
        unsigned pk = (unsigned)(rec & 0xffffffffL);
        int dst = (b << 12) | (int)(pk >> 17);
        int src = (int)(pk & 0x1ffffu);
        int pos = atomicAdd(&cursor[dst], 1);
        entries[pos] = (rec & 0xffffffff00000000L) | (unsigned)src;  // {w|src}
    }
}

// ---- gather (R1 winner): persistent waves, 8-deep chunks -------------------
__device__ void kG_body_bf(const unsigned short* __restrict__ hbatch,   // d_out
                           const unsigned short* __restrict__ hcw,      // ws, 64 KB
                           const long* __restrict__ entries,
                           const int* __restrict__ offsets, const int* __restrict__ counts,
                           const void* b_conv, const void* vq_grad, void* t,
                           float* __restrict__ infoP) {
    int tid = threadIdx.x;
    int l = tid & 63;
    int g = l >> 4;                 // edge-group 0..3
    int q = l & 15;                 // lane-in-group
    int c0 = q * 8;                 // 8 channels per lane
    int n = c0 >> 5, e0 = c0 & 31;
    const unsigned short* gb = (const unsigned short*)vq_grad + (long)n * MM * DD + e0;

    int wid = (int)((blockIdx.x * blockDim.x + tid) >> 6);
    int nw  = (int)((gridDim.x * blockDim.x) >> 6);

    for (int i = wid; i < BN; i += nw) {
        int start = __builtin_amdgcn_readfirstlane(offsets[i]);
        int deg   = __builtin_amdgcn_readfirstlane(counts[i]);
        const long* ep = entries + start;

        float hi[8];                // own row (batch), for info term
        unpack8(*(const int4*)(hbatch + (long)i * CC + c0), hi);
        float acc[8] = {0.f, 0.f, 0.f, 0.f, 0.f, 0.f, 0.f, 0.f};
        float info = 0.f;

        for (int j = 0; j < deg; j += 32) {
            int src[8]; float wj[8];
#pragma unroll
            for (int u = 0; u < 8; u++) {
                int idx = j + 4 * u + g;
                long e8 = __builtin_nontemporal_load(ep + (idx < deg ? idx : deg - 1));
                src[u] = (int)(unsigned)(e8 & 0xffffffffL);
                wj[u]  = (idx < deg) ? __int_as_float((int)(e8 >> 32)) : 0.f;
            }
#pragma unroll
            for (int u = 0; u < 8; u++) {
                int4 hv;
                if (src[u] < BN) {
                    hv = *(const int4*)(hbatch + (long)src[u] * CC + c0);
                } else {
                    hv = *(const int4*)(hcw + (long)(src[u] - BN) * CC + c0);
                    if (wj[u] != 0.f) {
                        int4 gv = *(const int4*)(gb + (long)(src[u] - BN) * DD);
                        info += wj[u] * dot8(hi, gv);
                    }
                }
                fma8(acc, wj[u], hv);
            }
        }
        // merge the 4 group-accumulators
#pragma unroll
        for (int k = 0; k < 8; k++) {
            acc[k] += __shfl_xor(acc[k], 16);
            acc[k] += __shfl_xor(acc[k], 32);
        }
        for (int off = 32; off; off >>= 1) info += __shfl_xor(info, off);
        if (l == 0) infoP[i] = info;    // plain store — NO atomic
        if (g == 0) {                   // lanes 0-15 write the 256 B t row
            float bc[8];
            unpack8(*(const int4*)((const unsigned short*)b_conv + n * DD + e0), bc);
            unsigned o[4];
#pragma unroll
            for (int d = 0; d < 4; d++)
                o[d] = ((unsigned)IO<1>::f2b(acc[2 * d] + bc[2 * d])) |
                       (((unsigned)IO<1>::f2b(acc[2 * d + 1] + bc[2 * d + 1])) << 16);
            *(int4*)((unsigned short*)t + (long)i * CC + c0) = make_int4(o[0], o[1], o[2], o[3]);
        }
    }
}

// fp32 fallback (correctness-only path)
__device__ void kG_body_f32(const float* __restrict__ hbatch, const float* __restrict__ hcw,
                            const long* __restrict__ entries,
                            const int* __restrict__ offsets, const int* __restrict__ counts,
                            const void* b_conv, const void* vq_grad, void* t,
                            float* __restrict__ infoP) {
    int tid = threadIdx.x;
    int l = tid & 63;
    int c0 = 2 * l, n = c0 >> 5, e = c0 & 31;
    int wid = (int)((blockIdx.x * blockDim.x + tid) >> 6);
    int nw  = (int)((gridDim.x * blockDim.x) >> 6);
    for (int i = wid; i < BN; i += nw) {
        int start = __builtin_amdgcn_readfirstlane(offsets[i]);
        int deg   = __builtin_amdgcn_readfirstlane(counts[i]);
        const long* ep = entries + start;
        float2 hi = HIO<0>::ld(hbatch, i, l);
        long gbase = (long)n * MM * DD + e;
        float2 acc = make_float2(0.f, 0.f);
        float info = 0.f;
        for (int j = 0; j < deg; j++) {
            long e8 = ep[j];
            int sv = (int)(unsigned)(e8 & 0xffffffffL);
            float wj = __int_as_float((int)(e8 >> 32));
            const float* src = (sv < BN) ? (hbatch + (long)sv * CC)
                                         : (hcw + (long)(sv - BN) * CC);
            float2 hv = *(const float2*)(src + c0);
            acc.x += wj * hv.x;
            acc.y += wj * hv.y;
            if (sv >= BN) {
                float2 gv = IO<0>::ld2(vq_grad, gbase + (long)(sv - BN) * DD);
                info += wj * (hi.x * gv.x + hi.y * gv.y);
            }
        }
        float2 b2 = IO<0>::ld2(b_conv, n * DD + e);
        IO<0>::st2(t, (long)i * CC + c0, make_float2(acc.x + b2.x, acc.y + b2.y));
        for (int off = 32; off; off >>= 1) info += __shfl_xor(info, off);
        if (l == 0) infoP[i] = info;
    }
}
__global__ __launch_bounds__(256, 8) void kGather(const int* flag, const float* hout,
                                                  const float* hcw, const long* entries,
                                                  const int* offsets, const int* counts,
                                                  const void* b_conv, const void* vq_grad,
                                                  void* t, float* infoP) {
    if (*flag) kG_body_bf((const unsigned short*)hout, (const unsigned short*)hcw,
                          entries, offsets, counts, b_conv, vq_grad, t, infoP);
    else       kG_body_f32(hout, hcw, entries, offsets, counts, b_conv, vq_grad, t, infoP);
}

// ---- reduce infoP[BN] -> ibAcc (49 blocks, one atomic each) ----------------
__global__ __launch_bounds__(1024) void kRed(const float* __restrict__ infoP, float* ibAcc) {
    __shared__ float s[1024];
    int tid = threadIdx.x;
    int i = blockIdx.x * 1024 + tid;
    s[tid] = (i < BN) ? infoP[i] : 0.f;
    __syncthreads();
    for (int st = 512; st; st >>= 1) {
        if (tid < st) s[tid] += s[tid + st];
        __syncthreads();
    }
    if (tid == 0) atomicAdd(ibAcc, s[0]);
}

// ---- FC (bf16): MFMA GEMM. Y = T @ W_fc + b_fc + X_B -----------------------
// 4 waves/block, wave owns 16 rows x 128 cols: 8 acc tiles, 32 mfma 16x16x32.
// A and B frags both use contiguous-8-k per lane (same k permutation for A and
// B cancels — sum over k is permutation-invariant). C/D: col=lane&15,
// row=(lane>>4)*4+reg (m89-verified). W^T staged in LDS once per block.
__global__ __launch_bounds__(256) void kFCmfma(const int* flag, const void* t,
                                               const void* W_fc, const void* b_fc,
                                               const void* X_B, void* Y) {
    if (!*flag) return;
    __shared__ unsigned short sWT[CC * CC];   // W^T: [n][k], 32 KB
    int tid = threadIdx.x;
    const unsigned short* W = (const unsigned short*)W_fc;
    for (int base = tid * 8; base < CC * CC; base += 256 * 8) {
        int k = base >> 7, n0 = base & 127;
        bf16x8 wv = *(const bf16x8*)(W + base);      // W[k][n0..n0+7]
#pragma unroll
        for (int j = 0; j < 8; j++) sWT[(n0 + j) * CC + k] = (unsigned short)wv[j];
    }
    __syncthreads();

    int w = tid >> 6, l = tid & 63;
    int m = l & 15, kg = l >> 4;               // C/D: col=m, rows kg*4+reg
    int r0 = blockIdx.x * 64 + w * 16;         // wave's 16-row stripe
    int rowA = r0 + m;
    const unsigned short* T = (const unsigned short*)t;
    f32x4 acc[8];
#pragma unroll
    for (int nt = 0; nt < 8; nt++) acc[nt] = (f32x4){0.f, 0.f, 0.f, 0.f};
    bool okA = rowA < BN;
#pragma unroll
    for (int ks = 0; ks < 4; ks++) {
        int k0 = ks * 32 + kg * 8;
        bf16x8 a = (bf16x8){0, 0, 0, 0, 0, 0, 0, 0};
        if (okA) a = *(const bf16x8*)(T + (long)rowA * CC + k0);
#pragma unroll
        for (int nt = 0; nt < 8; nt++) {
            bf16x8 b = *(const bf16x8*)(sWT + (nt * 16 + m) * CC + k0);
            acc[nt] = __builtin_amdgcn_mfma_f32_16x16x32_bf16(a, b, acc[nt], 0, 0, 0);
        }
    }
    // epilogue: + b_fc + X_B, bf16 store
    const unsigned short* XB = (const unsigned short*)X_B;
    unsigned short* Yp = (unsigned short*)Y;
#pragma unroll
    for (int nt = 0; nt < 8; nt++) {
        int col = nt * 16 + m;
        float bf = IO<1>::ld(b_fc, col);
#pragma unroll
        for (int reg = 0; reg < 4; reg++) {
            int r = r0 + kg * 4 + reg;
            if (r < BN) {
                float xb = IO<1>::b2f(XB[(long)r * CC + col]);
                Yp[(long)r * CC + col] = IO<1>::f2b(acc[nt][reg] + bf + xb);
            }
        }
    }
}

// ---- FC (fp32 fallback): original VALU version -----------------------------
__global__ __launch_bounds__(512) void kFCf32(const int* flag, const void* t,
                                              const void* W_fc, const void* b_fc,
                                              const void* X_B, void* Y) {
    if (*flag) return;
    __shared__ float sT[32 * CC];
    __shared__ float sW[32 * CC];
    int tid = threadIdx.x;
    int w = tid >> 6, l = tid & 63;
    int c0 = 2 * l;
    int r0 = blockIdx.x * 32;
    for (int k = tid; k < 32 * CC / 2; k += 512) {
        int row = k >> 6, c = (k & 63) * 2;
        float2 v = make_float2(0.f, 0.f);
        if (r0 + row < BN) v = IO<0>::ld2(t, (long)(r0 + row) * CC + c);
        sT[row * CC + c] = v.x;
        sT[row * CC + c + 1] = v.y;
    }
    float2 y[4];
#pragma unroll
    for (int rr = 0; rr < 4; rr++) y[rr] = make_float2(0.f, 0.f);
    for (int ch = 0; ch < 4; ch++) {
        __syncthreads();
        for (int k = tid; k < 32 * CC / 2; k += 512) {
            int cc = k >> 6, c = (k & 63) * 2;
            float2 v = IO<0>::ld2(W_fc, (long)(ch * 32 + cc) * CC + c);
            sW[cc * CC + c] = v.x;
            sW[cc * CC + c + 1] = v.y;
        }
        __syncthreads();
#pragma unroll 8
        for (int cc = 0; cc < 32; cc++) {
            float2 wv = *(const float2*)&sW[cc * CC + c0];
#pragma unroll
            for (int rr = 0; rr < 4; rr++) {
                float tv = sT[(w * 4 + rr) * CC + ch * 32 + cc];
                y[rr].x += tv * wv.x;
                y[rr].y += tv * wv.y;
            }
        }
    }
    float2 bf = IO<0>::ld2(b_fc, c0);
#pragma unroll
    for (int rr = 0; rr < 4; rr++) {
        int r = r0 + w * 4 + rr;
        if (r < BN) {
            float2 xb = IO<0>::ld2(X_B, (long)r * CC + c0);
            IO<0>::st2(Y, (long)r * CC + c0,
                       make_float2(y[rr].x + bf.x + xb.x, y[rr].y + bf.y + xb.y));
        }
    }
}

// ---------------- finalize: + b_conv·vq_grad term, scale by wr --------------
template <int ISBF>
__device__ void kF_body(const void* b_conv, const void* vq_grad, const void* warm,
                        const float* ibAcc, void* out, float* sred) {
    int tid = threadIdx.x;
    float a = 0.f;
    for (int idx = tid; idx < NBR * MM * DD; idx += 256) {
        int nn = idx >> 13, dd = idx & 31;
        a += IO<ISBF>::ld(b_conv, nn * DD + dd) * IO<ISBF>::ld(vq_grad, idx);
    }
    sred[tid] = a;
    __syncthreads();
    for (int s = 128; s; s >>= 1) {
        if (tid < s) sred[tid] += sred[tid + s];
        __syncthreads();
    }
    if (tid == 0) {
        float wr = IO<ISBF>::ld(warm, 0);
        IO<ISBF>::st(out, (long)BN * CC, wr * (ibAcc[0] + sred[0]));
    }
}
__global__ __launch_bounds__(256) void kFinal(const int* flag, const void* b_conv,
                                              const void* vq_grad, const void* warm,
                                              const float* ibAcc, void* out) {
    __shared__ float sred[256];
    if (*flag) kF_body<1>(b_conv, vq_grad, warm, ibAcc, out, sred);
    else       kF_body<0>(b_conv, vq_grad, warm, ibAcc, out, sred);
}

// ---------------- launch --------------------------------------------------
extern "C" void kernel_launch(void* const* d_in, const int* in_sizes, int n_in,
                              void* d_out, int out_size, void* d_ws, size_t ws_size,
                              hipStream_t stream) {
    (void)in_sizes; (void)n_in; (void)out_size;
    const void* X_B      = d_in[0];
    const int*  esrc_bb  = (const int*)d_in[1];
    const int*  edst_bb  = (const int*)d_in[2];
    const void* ew_bb    = d_in[3];
    const int*  esrc_bm  = (const int*)d_in[4];
    const int*  edst_bm  = (const int*)d_in[5];
    const void* ew_bm    = d_in[6];
    const int*  c_idx    = (const int*)d_in[7];
    const void* warm     = d_in[8];
    const void* codebook = d_in[9];
    const void* vq_grad  = d_in[10];
    const void* W_conv   = d_in[11];
    const void* b_conv   = d_in[12];
    const void* W_fc     = d_in[13];
    const void* b_fc     = d_in[14];

    char* ws = (char*)d_ws;
    float* hcw     = (float*)ws;  ws += (size_t)MM * CC * 4;       // 128 KiB (fp32 worst)
    float* tbuf    = (float*)ws;  ws += (size_t)BN * CC * 4;       // 25.6 MB (recs alias)
    long*  entries = (long*)ws;   ws += (size_t)NEDGE * 8;         // 16 MB
    int*   counts  = (int*)ws;    ws += (size_t)BN * 4;
    int*   offsets = (int*)ws;    ws += (size_t)BN * 4;
    int*   cursor  = (int*)ws;    ws += (size_t)BN * 4;
    float* infoP   = (float*)ws;  ws += (size_t)BN * 4;            // 200 KB partials
    int*   tileSum = (int*)ws;    ws += 64 * 4;
    int*   areaCur = (int*)ws;    ws += (size_t)NAREA * 16 * 4;    // 13.3 KB (64B-padded)
    float* ibAcc   = (float*)ws;  ws += 16;
    int*   flag    = (int*)ws;    ws += 16;
    if ((size_t)(ws - (char*)d_ws) > ws_size) return;  // ws too small: bail

    long* recs = (long*)tbuf;      // records alias tbuf (dead until kGather)
    float* hout = (float*)d_out;   // batch h-rows live in d_out until kFC overwrites

    hipMemsetAsync(counts, 0, (size_t)BN * 4, stream);
    hipMemsetAsync(areaCur, 0, (size_t)NAREA * 16 * 4, stream);
    hipMemsetAsync(ibAcc, 0, 4, stream);
    kDetect<<<1, 1, 0, stream>>>(warm, flag);
    kA<<<ROWS / 4, 256, 0, stream>>>(flag, X_B, codebook, W_conv, warm, hout, hcw);
    kP1<<<1024, 256, 0, stream>>>(flag, esrc_bb, edst_bb, ew_bb, esrc_bm, edst_bm,
                                  ew_bm, c_idx, counts, areaCur, recs);
    kScan1<<<SCAN_BLOCKS, 1024, 0, stream>>>(counts, offsets, tileSum);
    kScan2<<<1, 1, 0, stream>>>(tileSum);
    kScan3<<<SCAN_BLOCKS, 1024, 0, stream>>>(offsets, tileSum, cursor);
    kP2<<<NAREA, 256, 0, stream>>>(areaCur, recs, cursor, entries);
    kGather<<<2048, 256, 0, stream>>>(flag, hout, hcw, entries, offsets, counts,
                                      b_conv, vq_grad, tbuf, infoP);
    kRed<<<SCAN_BLOCKS, 1024, 0, stream>>>(infoP, ibAcc);
    kFCmfma<<<(BN + 63) / 64, 256, 0, stream>>>(flag, tbuf, W_fc, b_fc, X_B, d_out);
    kFCf32<<<(BN + 31) / 32, 512, 0, stream>>>(flag, tbuf, W_fc, b_fc, X_B, d_out);
    kFinal<<<1, 256, 0, stream>>>(flag, b_conv, vq_grad, warm, ibAcc, d_out);
}

// Round 8
// 542.147 us; speedup vs baseline: 1.8066x; 1.1508x over previous
//
#include <hip/hip_runtime.h>
#include <hip/hip_bf16.h>

#define BN    50000
#define NBR   4
#define MM    256
#define DD    32
#define CC    128
#define EE    1000000
#define ROWS  (BN + MM)          // 50256
#define NEDGE (2 * EE)
#define SCAN_BLOCKS 49           // ceil(50000/1024)

// ---- bucketed CSR build geometry -------------------------------------------
#define NBUK  13                 // dst bucket = dst >> 12 (4096 dsts, ~1.3 MB CSR window)
#define NSG   16                 // subgroups per bucket
#define NAREA (NBUK * NSG)       // 208 record areas
#define ACAP  15360              // records per area (mean ~9.6K, huge margin)

// ---- runtime dtype detect (inline, no kDetect dispatch) --------------------
// bf16(1.0) first u16 = 0x3F80 ; fp32(1.0f) first u16 = 0x0000.
static __device__ inline int isBF(const void* warm) {
    return ((const unsigned short*)warm)[0] == 0x3F80u;
}

// ---------------- dtype abstraction ----------------------------------------
template <int ISBF> struct IO;

template <> struct IO<0> {
    static __device__ float ld(const void* p, long i) { return ((const float*)p)[i]; }
    static __device__ float2 ld2(const void* p, long i) {
        const float* f = (const float*)p + i;
        return make_float2(f[0], f[1]);
    }
    static __device__ void st(void* p, long i, float v) { ((float*)p)[i] = v; }
    static __device__ void st2(void* p, long i, float2 v) {
        float* f = (float*)p + i; f[0] = v.x; f[1] = v.y;
    }
};

template <> struct IO<1> {
    static __device__ float b2f(unsigned short u) {
        return __uint_as_float(((unsigned)u) << 16);
    }
    static __device__ unsigned short f2b(float f) {  // round-to-nearest-even
        unsigned x = __float_as_uint(f);
        unsigned r = x + 0x7fffu + ((x >> 16) & 1u);
        return (unsigned short)(r >> 16);
    }
    static __device__ float ld(const void* p, long i) {
        return b2f(((const unsigned short*)p)[i]);
    }
    static __device__ float2 ld2(const void* p, long i) {  // i must be even
        unsigned v = *(const unsigned*)((const unsigned short*)p + i);
        return make_float2(b2f((unsigned short)(v & 0xffffu)),
                           b2f((unsigned short)(v >> 16)));
    }
    static __device__ void st(void* p, long i, float v) {
        ((unsigned short*)p)[i] = f2b(v);
    }
    static __device__ void st2(void* p, long i, float2 v) {
        unsigned o = ((unsigned)f2b(v.x)) | (((unsigned)f2b(v.y)) << 16);
        *(unsigned*)((unsigned short*)p + i) = o;
    }
};

// ---------------- h storage helpers (row-major) ----------------------------
template <int ISBF> struct HIO;
template <> struct HIO<0> {
    static __device__ float2 ld(const float* h, long row, int l) {
        return *(const float2*)(h + row * CC + 2 * l);
    }
    static __device__ void st(float* h, long row, int l, float2 v) {
        *(float2*)(h + row * CC + 2 * l) = v;
    }
};
template <> struct HIO<1> {
    static __device__ float2 ld(const float* h, long row, int l) {
        unsigned u = ((const unsigned*)h)[row * (CC / 2) + l];
        return make_float2(IO<1>::b2f((unsigned short)(u & 0xffffu)),
                           IO<1>::b2f((unsigned short)(u >> 16)));
    }
    static __device__ void st(float* h, long row, int l, float2 v) {
        unsigned o = ((unsigned)IO<1>::f2b(v.x)) | (((unsigned)IO<1>::f2b(v.y)) << 16);
        ((unsigned*)h)[row * (CC / 2) + l] = o;
    }
};

// ---------------- bf16 8-channel helpers (int4 = 8 bf16) --------------------
static __device__ inline void unpack8(int4 v, float* f) {
    unsigned a = (unsigned)v.x, b = (unsigned)v.y, c = (unsigned)v.z, d = (unsigned)v.w;
    f[0] = IO<1>::b2f((unsigned short)(a & 0xffffu)); f[1] = IO<1>::b2f((unsigned short)(a >> 16));
    f[2] = IO<1>::b2f((unsigned short)(b & 0xffffu)); f[3] = IO<1>::b2f((unsigned short)(b >> 16));
    f[4] = IO<1>::b2f((unsigned short)(c & 0xffffu)); f[5] = IO<1>::b2f((unsigned short)(c >> 16));
    f[6] = IO<1>::b2f((unsigned short)(d & 0xffffu)); f[7] = IO<1>::b2f((unsigned short)(d >> 16));
}
static __device__ inline void fma8(float* acc, float w, int4 v) {
    float f[8]; unpack8(v, f);
#pragma unroll
    for (int k = 0; k < 8; k++) acc[k] += w * f[k];
}
static __device__ inline float dot8(const float* hi, int4 v) {
    float f[8]; unpack8(v, f);
    float s = 0.f;
#pragma unroll
    for (int k = 0; k < 8; k++) s += hi[k] * f[k];
    return s;
}

// ---------------- MFMA types -------------------------------------------------
typedef short bf16x8 __attribute__((ext_vector_type(8)));
typedef float f32x4  __attribute__((ext_vector_type(4)));

// ---------------- kernel A ---------------------------------------------------
// h batch rows (r < BN) -> d_out (row-major); codeword rows -> ws hcw
template <int ISBF>
__device__ void kA_body(const void* X_B, const void* codebook, const void* W_conv,
                        const void* warm, float* __restrict__ hout,
                        float* __restrict__ hcw, float* sW, float* sX) {
    int tid = threadIdx.x;
    int w = tid >> 6, l = tid & 63;
    for (int k = tid; k < NBR * DD * DD; k += 256)
        sW[k] = IO<ISBF>::ld(W_conv, k);
    int r = blockIdx.x * 4 + w;
    int c0 = 2 * l, n = c0 >> 5, e = c0 & 31;
    float2 x2;
    if (r < BN) {
        x2 = IO<ISBF>::ld2(X_B, (long)r * CC + c0);
    } else {
        int m = r - BN;
        float wr = IO<ISBF>::ld(warm, 0);
        x2 = IO<ISBF>::ld2(codebook, (long)n * MM * DD + m * DD + e);
        x2.x *= wr; x2.y *= wr;
    }
    sX[w * CC + c0] = x2.x;
    sX[w * CC + c0 + 1] = x2.y;
    __syncthreads();
    float2 acc = make_float2(0.f, 0.f);
#pragma unroll
    for (int d = 0; d < DD; d++) {
        float xv = sX[w * CC + n * DD + d];
        float2 wv = *(const float2*)&sW[n * DD * DD + d * DD + e];
        acc.x += xv * wv.x;
        acc.y += xv * wv.y;
    }
    if (r < BN) HIO<ISBF>::st(hout, r, l, acc);
    else        HIO<ISBF>::st(hcw, r - BN, l, acc);
}
__global__ __launch_bounds__(256) void kA(const void* X_B, const void* codebook,
                                          const void* W_conv, const void* warm,
                                          float* hout, float* hcw) {
    __shared__ float sW[NBR * DD * DD];
    __shared__ float sX[4 * CC];
    if (isBF(warm)) kA_body<1>(X_B, codebook, W_conv, warm, hout, hcw, sW, sX);
    else            kA_body<0>(X_B, codebook, W_conv, warm, hout, hcw, sW, sX);
}

// ---- P1: stream edges once -> dst histogram + bucketed 8 B records ---------
// LDS staging + coalesced area appends (verified correct R13/R14).
template <int ISBF>
__device__ void kP1_body(const int* esrc_bb, const int* edst_bb, const void* ew_bb,
                         const int* esrc_bm, const int* edst_bm, const void* ew_bm,
                         const int* c_idx, int* __restrict__ counts,
                         int* __restrict__ areaCur, long* __restrict__ recs,
                         long* stage, int* lcnt) {
    int tid = threadIdx.x;
    int wv = tid >> 6, lane = tid & 63;
    int sg = blockIdx.x & (NSG - 1);
    for (long i0 = (long)blockIdx.x * 256; i0 < NEDGE; i0 += (long)gridDim.x * 256) {
        if (tid < NBUK) lcnt[tid] = 0;
        __syncthreads();
        long i = i0 + tid;
        if (i < NEDGE) {
            int src, dst; float w;
            if (i < EE) {
                src = esrc_bb[i]; dst = edst_bb[i]; w = IO<ISBF>::ld(ew_bb, i);
            } else {
                long j = i - EE;
                src = BN + c_idx[esrc_bm[j]]; dst = edst_bm[j]; w = IO<ISBF>::ld(ew_bm, j);
            }
            int b = dst >> 12;
            unsigned pk = ((unsigned)(dst & 4095) << 17) | (unsigned)src;
            long rec = ((long)__float_as_int(w) << 32) | (unsigned long long)pk;
            int slot = atomicAdd(&lcnt[b], 1);
            stage[b * 256 + slot] = rec;
            atomicAdd(&counts[dst], 1);
        }
        __syncthreads();
        // flush: wave wv handles buckets wv, wv+4, ...
        for (int bk = wv; bk < NBUK; bk += 4) {
            int cnt = lcnt[bk];
            if (cnt == 0) continue;
            int gb = 0;
            if (lane == 0) gb = atomicAdd(&areaCur[(bk * NSG + sg) * 16], cnt);
            gb = __shfl(gb, 0);
            long* dstp = recs + (long)(bk * NSG + sg) * ACAP + gb;
            for (int k = lane; k < cnt; k += 64) dstp[k] = stage[bk * 256 + k];
        }
        __syncthreads();
    }
}
__global__ __launch_bounds__(256) void kP1(const void* warm, const int* esrc_bb,
                                           const int* edst_bb, const void* ew_bb,
                                           const int* esrc_bm, const int* edst_bm,
                                           const void* ew_bm, const int* c_idx,
                                           int* counts, int* areaCur, long* recs) {
    __shared__ long stage[NBUK * 256];   // 26.6 KB
    __shared__ int lcnt[NBUK];
    if (isBF(warm)) kP1_body<1>(esrc_bb, edst_bb, ew_bb, esrc_bm, edst_bm, ew_bm,
                                c_idx, counts, areaCur, recs, stage, lcnt);
    else            kP1_body<0>(esrc_bb, edst_bb, ew_bb, esrc_bm, edst_bm, ew_bm,
                                c_idx, counts, areaCur, recs, stage, lcnt);
}

// ---------------- scan over counts[BN] (2 kernels; scan2 folded into scan3) --
__global__ __launch_bounds__(1024) void kScan1(const int* __restrict__ counts,
                                               int* __restrict__ offsets,
                                               int* __restrict__ tileSum) {
    __shared__ int s[1024];
    int tid = threadIdx.x;
    int i = blockIdx.x * 1024 + tid;
    int v = (i < BN) ? counts[i] : 0;
    s[tid] = v;
    __syncthreads();
    for (int off = 1; off < 1024; off <<= 1) {
        int x = (tid >= off) ? s[tid - off] : 0;
        __syncthreads();
        s[tid] += x;
        __syncthreads();
    }
    if (i < BN) offsets[i] = s[tid] - v;  // tile-local exclusive
    if (tid == 1023) tileSum[blockIdx.x] = s[tid];  // tile TOTAL
}
__global__ __launch_bounds__(1024) void kScan3(int* __restrict__ offsets,
                                               const int* __restrict__ tileSum,
                                               int* __restrict__ cursor) {
    __shared__ int sPre;
    int tid = threadIdx.x;
    if (tid < 64) {             // one wave computes exclusive prefix over tile totals
        int v = (tid < (int)blockIdx.x) ? tileSum[tid] : 0;
        for (int off = 32; off; off >>= 1) v += __shfl_down(v, off);
        if (tid == 0) sPre = v;
    }
    __syncthreads();
    int i = blockIdx.x * 1024 + tid;
    if (i < BN) {
        int o = offsets[i] + sPre;
        offsets[i] = o;
        cursor[i] = o;
    }
}

// ---- P2: distribute bucket records into CSR entries (208 blocks) -----------
__global__ __launch_bounds__(256) void kP2(const int* __restrict__ areaCur,
                                           const long* __restrict__ recs,
                                           int* __restrict__ cursor,
                                           long* __restrict__ entries) {
    int a = blockIdx.x;                 // a = b*NSG + sg
    int b = a / NSG;
    int n = areaCur[a * 16];
    const long* rp = recs + (long)a * ACAP;
    for (int k = threadIdx.x; k < n; k += 256) {
        long rec = rp[k];
        unsigned pk = (unsigned)(rec & 0xffffffffL);
        int dst = (b << 12) | (int)(pk >> 17);
        int src = (int)(pk & 0x1ffffu);
        int pos = atomicAdd(&cursor[dst], 1);
        entries[pos] = (rec & 0xffffffff00000000L) | (unsigned)src;  // {w|src}
    }
}

// ---- gather (R1 winner): persistent waves, 8-deep chunks -------------------
__device__ void kG_body_bf(const unsigned short* __restrict__ hbatch,   // d_out
                           const unsigned short* __restrict__ hcw,      // ws, 64 KB
                           const long* __restrict__ entries,
                           const int* __restrict__ offsets, const int* __restrict__ counts,
                           const void* b_conv, const void* vq_grad, void* t,
                           float* __restrict__ infoP) {
    int tid = threadIdx.x;
    int l = tid & 63;
    int g = l >> 4;                 // edge-group 0..3
    int q = l & 15;                 // lane-in-group
    int c0 = q * 8;                 // 8 channels per lane
    int n = c0 >> 5, e0 = c0 & 31;
    const unsigned short* gb = (const unsigned short*)vq_grad + (long)n * MM * DD + e0;

    int wid = (int)((blockIdx.x * blockDim.x + tid) >> 6);
    int nw  = (int)((gridDim.x * blockDim.x) >> 6);

    for (int i = wid; i < BN; i += nw) {
        int start = __builtin_amdgcn_readfirstlane(offsets[i]);
        int deg   = __builtin_amdgcn_readfirstlane(counts[i]);
        const long* ep = entries + start;

        float hi[8];                // own row (batch), for info term
        unpack8(*(const int4*)(hbatch + (long)i * CC + c0), hi);
        float acc[8] = {0.f, 0.f, 0.f, 0.f, 0.f, 0.f, 0.f, 0.f};
        float info = 0.f;

        for (int j = 0; j < deg; j += 32) {
            int src[8]; float wj[8];
#pragma unroll
            for (int u = 0; u < 8; u++) {
                int idx = j + 4 * u + g;
                long e8 = __builtin_nontemporal_load(ep + (idx < deg ? idx : deg - 1));
                src[u] = (int)(unsigned)(e8 & 0xffffffffL);
                wj[u]  = (idx < deg) ? __int_as_float((int)(e8 >> 32)) : 0.f;
            }
#pragma unroll
            for (int u = 0; u < 8; u++) {
                int4 hv;
                if (src[u] < BN) {
                    hv = *(const int4*)(hbatch + (long)src[u] * CC + c0);
                } else {
                    hv = *(const int4*)(hcw + (long)(src[u] - BN) * CC + c0);
                    if (wj[u] != 0.f) {
                        int4 gv = *(const int4*)(gb + (long)(src[u] - BN) * DD);
                        info += wj[u] * dot8(hi, gv);
                    }
                }
                fma8(acc, wj[u], hv);
            }
        }
        // merge the 4 group-accumulators
#pragma unroll
        for (int k = 0; k < 8; k++) {
            acc[k] += __shfl_xor(acc[k], 16);
            acc[k] += __shfl_xor(acc[k], 32);
        }
        for (int off = 32; off; off >>= 1) info += __shfl_xor(info, off);
        if (l == 0) infoP[i] = info;    // plain store — NO atomic
        if (g == 0) {                   // lanes 0-15 write the 256 B t row
            float bc[8];
            unpack8(*(const int4*)((const unsigned short*)b_conv + n * DD + e0), bc);
            unsigned o[4];
#pragma unroll
            for (int d = 0; d < 4; d++)
                o[d] = ((unsigned)IO<1>::f2b(acc[2 * d] + bc[2 * d])) |
                       (((unsigned)IO<1>::f2b(acc[2 * d + 1] + bc[2 * d + 1])) << 16);
            *(int4*)((unsigned short*)t + (long)i * CC + c0) = make_int4(o[0], o[1], o[2], o[3]);
        }
    }
}

// fp32 fallback (correctness-only path)
__device__ void kG_body_f32(const float* __restrict__ hbatch, const float* __restrict__ hcw,
                            const long* __restrict__ entries,
                            const int* __restrict__ offsets, const int* __restrict__ counts,
                            const void* b_conv, const void* vq_grad, void* t,
                            float* __restrict__ infoP) {
    int tid = threadIdx.x;
    int l = tid & 63;
    int c0 = 2 * l, n = c0 >> 5, e = c0 & 31;
    int wid = (int)((blockIdx.x * blockDim.x + tid) >> 6);
    int nw  = (int)((gridDim.x * blockDim.x) >> 6);
    for (int i = wid; i < BN; i += nw) {
        int start = __builtin_amdgcn_readfirstlane(offsets[i]);
        int deg   = __builtin_amdgcn_readfirstlane(counts[i]);
        const long* ep = entries + start;
        float2 hi = HIO<0>::ld(hbatch, i, l);
        long gbase = (long)n * MM * DD + e;
        float2 acc = make_float2(0.f, 0.f);
        float info = 0.f;
        for (int j = 0; j < deg; j++) {
            long e8 = ep[j];
            int sv = (int)(unsigned)(e8 & 0xffffffffL);
            float wj = __int_as_float((int)(e8 >> 32));
            const float* src = (sv < BN) ? (hbatch + (long)sv * CC)
                                         : (hcw + (long)(sv - BN) * CC);
            float2 hv = *(const float2*)(src + c0);
            acc.x += wj * hv.x;
            acc.y += wj * hv.y;
            if (sv >= BN) {
                float2 gv = IO<0>::ld2(vq_grad, gbase + (long)(sv - BN) * DD);
                info += wj * (hi.x * gv.x + hi.y * gv.y);
            }
        }
        float2 b2 = IO<0>::ld2(b_conv, n * DD + e);
        IO<0>::st2(t, (long)i * CC + c0, make_float2(acc.x + b2.x, acc.y + b2.y));
        for (int off = 32; off; off >>= 1) info += __shfl_xor(info, off);
        if (l == 0) infoP[i] = info;
    }
}
__global__ __launch_bounds__(256, 8) void kGather(const void* warm, const float* hout,
                                                  const float* hcw, const long* entries,
                                                  const int* offsets, const int* counts,
                                                  const void* b_conv, const void* vq_grad,
                                                  void* t, float* infoP) {
    if (isBF(warm)) kG_body_bf((const unsigned short*)hout, (const unsigned short*)hcw,
                               entries, offsets, counts, b_conv, vq_grad, t, infoP);
    else            kG_body_f32(hout, hcw, entries, offsets, counts, b_conv, vq_grad, t, infoP);
}

// ---- reduce infoP[BN] -> ibAcc (49 blocks, one atomic each) ----------------
__global__ __launch_bounds__(1024) void kRed(const float* __restrict__ infoP, float* ibAcc) {
    __shared__ float s[1024];
    int tid = threadIdx.x;
    int i = blockIdx.x * 1024 + tid;
    s[tid] = (i < BN) ? infoP[i] : 0.f;
    __syncthreads();
    for (int st = 512; st; st >>= 1) {
        if (tid < st) s[tid] += s[tid + st];
        __syncthreads();
    }
    if (tid == 0) atomicAdd(ibAcc, s[0]);
}

// ---- FC (bf16): MFMA GEMM. Y = T @ W_fc + b_fc + X_B -----------------------
// R7 post-mortem: the MFMA math was fine but the epilogue's per-lane scalar
// 2 B stores/loads (stride 256 B) caused ~4x line RMW amplification — MFMA
// gain eaten. Fix: barrier after k-loop, reuse sWT (32 KB) as fp32 scratch
// (4 waves x 16x128 exactly), transpose acc tiles through LDS, then fully
// vectorized int4 X_B loads + Y stores. Per-element math order unchanged.
__global__ __launch_bounds__(256) void kFCmfma(const void* warm, const void* t,
                                               const void* W_fc, const void* b_fc,
                                               const void* X_B, void* Y) {
    if (!isBF(warm)) return;
    __shared__ unsigned short sWT[CC * CC];   // W^T [n][k] 32 KB; later fp32 scratch
    int tid = threadIdx.x;
    const unsigned short* W = (const unsigned short*)W_fc;
    for (int base = tid * 8; base < CC * CC; base += 256 * 8) {
        int k = base >> 7, n0 = base & 127;
        bf16x8 wv = *(const bf16x8*)(W + base);      // W[k][n0..n0+7]
#pragma unroll
        for (int j = 0; j < 8; j++) sWT[(n0 + j) * CC + k] = (unsigned short)wv[j];
    }
    __syncthreads();

    int w = tid >> 6, l = tid & 63;
    int m = l & 15, kg = l >> 4;               // C/D: col=m, rows kg*4+reg
    int r0 = blockIdx.x * 64 + w * 16;         // wave's 16-row stripe
    int rowA = r0 + m;
    const unsigned short* T = (const unsigned short*)t;
    f32x4 acc[8];
#pragma unroll
    for (int nt = 0; nt < 8; nt++) acc[nt] = (f32x4){0.f, 0.f, 0.f, 0.f};
    bool okA = rowA < BN;
#pragma unroll
    for (int ks = 0; ks < 4; ks++) {
        int k0 = ks * 32 + kg * 8;
        bf16x8 a = (bf16x8){0, 0, 0, 0, 0, 0, 0, 0};
        if (okA) a = *(const bf16x8*)(T + (long)rowA * CC + k0);
#pragma unroll
        for (int nt = 0; nt < 8; nt++) {
            bf16x8 b = *(const bf16x8*)(sWT + (nt * 16 + m) * CC + k0);
            acc[nt] = __builtin_amdgcn_mfma_f32_16x16x32_bf16(a, b, acc[nt], 0, 0, 0);
        }
    }
    // epilogue: transpose via LDS scratch, then coalesced vector loads/stores
    __syncthreads();                            // all waves done reading sWT
    float* S = ((float*)sWT) + w * (16 * CC);   // this wave's 16x128 fp32 tile
#pragma unroll
    for (int nt = 0; nt < 8; nt++)
#pragma unroll
        for (int reg = 0; reg < 4; reg++)
            S[(kg * 4 + reg) * CC + nt * 16 + m] = acc[nt][reg];
    __syncthreads();                            // simple block-wide publish

    int rr = l >> 2;                // row 0..15 within wave tile
    int cq = (l & 3) * 32;          // 32-col slice per lane
    int r = r0 + rr;
    if (r < BN) {
        const unsigned short* xbp = (const unsigned short*)X_B + (long)r * CC + cq;
        const unsigned short* bfp = (const unsigned short*)b_fc + cq;
        unsigned short* yp = (unsigned short*)Y + (long)r * CC + cq;
        const float* Sp = S + rr * CC + cq;
#pragma unroll
        for (int h8 = 0; h8 < 4; h8++) {        // 4 x 8 channels
            float xf[8], bf[8];
            unpack8(*(const int4*)(xbp + h8 * 8), xf);
            unpack8(*(const int4*)(bfp + h8 * 8), bf);
            unsigned o[4];
#pragma unroll
            for (int d = 0; d < 4; d++) {
                float v0 = Sp[h8 * 8 + 2 * d]     + bf[2 * d]     + xf[2 * d];
                float v1 = Sp[h8 * 8 + 2 * d + 1] + bf[2 * d + 1] + xf[2 * d + 1];
                o[d] = ((unsigned)IO<1>::f2b(v0)) | (((unsigned)IO<1>::f2b(v1)) << 16);
            }
            *(int4*)(yp + h8 * 8) = make_int4(o[0], o[1], o[2], o[3]);
        }
    }
}

// ---- FC (fp32 fallback): original VALU version -----------------------------
__global__ __launch_bounds__(512) void kFCf32(const void* warm, const void* t,
                                              const void* W_fc, const void* b_fc,
                                              const void* X_B, void* Y) {
    if (isBF(warm)) return;
    __shared__ float sT[32 * CC];
    __shared__ float sW[32 * CC];
    int tid = threadIdx.x;
    int w = tid >> 6, l = tid & 63;
    int c0 = 2 * l;
    int r0 = blockIdx.x * 32;
    for (int k = tid; k < 32 * CC / 2; k += 512) {
        int row = k >> 6, c = (k & 63) * 2;
        float2 v = make_float2(0.f, 0.f);
        if (r0 + row < BN) v = IO<0>::ld2(t, (long)(r0 + row) * CC + c);
        sT[row * CC + c] = v.x;
        sT[row * CC + c + 1] = v.y;
    }
    float2 y[4];
#pragma unroll
    for (int rr = 0; rr < 4; rr++) y[rr] = make_float2(0.f, 0.f);
    for (int ch = 0; ch < 4; ch++) {
        __syncthreads();
        for (int k = tid; k < 32 * CC / 2; k += 512) {
            int cc = k >> 6, c = (k & 63) * 2;
            float2 v = IO<0>::ld2(W_fc, (long)(ch * 32 + cc) * CC + c);
            sW[cc * CC + c] = v.x;
            sW[cc * CC + c + 1] = v.y;
        }
        __syncthreads();
#pragma unroll 8
        for (int cc = 0; cc < 32; cc++) {
            float2 wv = *(const float2*)&sW[cc * CC + c0];
#pragma unroll
            for (int rr = 0; rr < 4; rr++) {
                float tv = sT[(w * 4 + rr) * CC + ch * 32 + cc];
                y[rr].x += tv * wv.x;
                y[rr].y += tv * wv.y;
            }
        }
    }
    float2 bf = IO<0>::ld2(b_fc, c0);
#pragma unroll
    for (int rr = 0; rr < 4; rr++) {
        int r = r0 + w * 4 + rr;
        if (r < BN) {
            float2 xb = IO<0>::ld2(X_B, (long)r * CC + c0);
            IO<0>::st2(Y, (long)r * CC + c0,
                       make_float2(y[rr].x + bf.x + xb.x, y[rr].y + bf.y + xb.y));
        }
    }
}

// ---------------- finalize: + b_conv·vq_grad term, scale by wr --------------
template <int ISBF>
__device__ void kF_body(const void* b_conv, const void* vq_grad, const void* warm,
                        const float* ibAcc, void* out, float* sred) {
    int tid = threadIdx.x;
    float a = 0.f;
    for (int idx = tid; idx < NBR * MM * DD; idx += 256) {
        int nn = idx >> 13, dd = idx & 31;
        a += IO<ISBF>::ld(b_conv, nn * DD + dd) * IO<ISBF>::ld(vq_grad, idx);
    }
    sred[tid] = a;
    __syncthreads();
    for (int s = 128; s; s >>= 1) {
        if (tid < s) sred[tid] += sred[tid + s];
        __syncthreads();
    }
    if (tid == 0) {
        float wr = IO<ISBF>::ld(warm, 0);
        IO<ISBF>::st(out, (long)BN * CC, wr * (ibAcc[0] + sred[0]));
    }
}
__global__ __launch_bounds__(256) void kFinal(const void* b_conv, const void* vq_grad,
                                              const void* warm, const float* ibAcc,
                                              void* out) {
    __shared__ float sred[256];
    if (isBF(warm)) kF_body<1>(b_conv, vq_grad, warm, ibAcc, out, sred);
    else            kF_body<0>(b_conv, vq_grad, warm, ibAcc, out, sred);
}

// ---------------- launch --------------------------------------------------
extern "C" void kernel_launch(void* const* d_in, const int* in_sizes, int n_in,
                              void* d_out, int out_size, void* d_ws, size_t ws_size,
                              hipStream_t stream) {
    (void)in_sizes; (void)n_in; (void)out_size;
    const void* X_B      = d_in[0];
    const int*  esrc_bb  = (const int*)d_in[1];
    const int*  edst_bb  = (const int*)d_in[2];
    const void* ew_bb    = d_in[3];
    const int*  esrc_bm  = (const int*)d_in[4];
    const int*  edst_bm  = (const int*)d_in[5];
    const void* ew_bm    = d_in[6];
    const int*  c_idx    = (const int*)d_in[7];
    const void* warm     = d_in[8];
    const void* codebook = d_in[9];
    const void* vq_grad  = d_in[10];
    const void* W_conv   = d_in[11];
    const void* b_conv   = d_in[12];
    const void* W_fc     = d_in[13];
    const void* b_fc     = d_in[14];

    char* ws = (char*)d_ws;
    float* hcw     = (float*)ws;  ws += (size_t)MM * CC * 4;       // 128 KiB (fp32 worst)
    float* tbuf    = (float*)ws;  ws += (size_t)BN * CC * 4;       // 25.6 MB (recs alias)
    long*  entries = (long*)ws;   ws += (size_t)NEDGE * 8;         // 16 MB
    // zero-init region (ONE memset): counts | areaCur | ibAcc, contiguous
    int*   counts  = (int*)ws;    ws += (size_t)BN * 4;            // 200000 B
    int*   areaCur = (int*)ws;    ws += (size_t)NAREA * 16 * 4;    // 13312 B
    float* ibAcc   = (float*)ws;  ws += 16;
    size_t zbytes  = (size_t)BN * 4 + (size_t)NAREA * 16 * 4 + 16;
    int*   offsets = (int*)ws;    ws += (size_t)BN * 4;
    int*   cursor  = (int*)ws;    ws += (size_t)BN * 4;
    float* infoP   = (float*)ws;  ws += (size_t)BN * 4;            // 200 KB partials
    int*   tileSum = (int*)ws;    ws += 64 * 4;
    if ((size_t)(ws - (char*)d_ws) > ws_size) return;  // ws too small: bail

    long* recs = (long*)tbuf;      // records alias tbuf (dead until kGather)
    float* hout = (float*)d_out;   // batch h-rows live in d_out until kFC overwrites

    hipMemsetAsync(counts, 0, zbytes, stream);
    kA<<<ROWS / 4, 256, 0, stream>>>(X_B, codebook, W_conv, warm, hout, hcw);
    kP1<<<1024, 256, 0, stream>>>(warm, esrc_bb, edst_bb, ew_bb, esrc_bm, edst_bm,
                                  ew_bm, c_idx, counts, areaCur, recs);
    kScan1<<<SCAN_BLOCKS, 1024, 0, stream>>>(counts, offsets, tileSum);
    kScan3<<<SCAN_BLOCKS, 1024, 0, stream>>>(offsets, tileSum, cursor);
    kP2<<<NAREA, 256, 0, stream>>>(areaCur, recs, cursor, entries);
    kGather<<<2048, 256, 0, stream>>>(warm, hout, hcw, entries, offsets, counts,
                                      b_conv, vq_grad, tbuf, infoP);
    kRed<<<SCAN_BLOCKS, 1024, 0, stream>>>(infoP, ibAcc);
    kFCmfma<<<(BN + 63) / 64, 256, 0, stream>>>(warm, tbuf, W_fc, b_fc, X_B, d_out);
    kFCf32<<<(BN + 31) / 32, 512, 0, stream>>>(warm, tbuf, W_fc, b_fc, X_B, d_out);
    kFinal<<<1, 256, 0, stream>>>(b_conv, vq_grad, warm, ibAcc, d_out);
}